// Round 6
// baseline (744.360 us; speedup 1.0000x reference)
//
#include <hip/hip_runtime.h>

// BiGRU, B=512, T=512, D=16, H=64.
// Backward direction needs only ONE cell step (ys_b[0] = GRUCell(x[:,T-1,:], 0)).
//
// Round-5 lesson: 1 batch/wave is latency-bound: ~1550 of 2265 cyc/step BOTH
// resident waves stalled (DS round-trips on the serial chain, 0.5 waves/SIMD
// => no TLP, no ILP). TLP is structurally capped (512 chains < 1024 SIMDs), so:
//
// This version: TWO batches per wave (256 blocks x 64 thr), zero barriers:
//  - ALL 192 recurrent weight floats in VGPRs, SHARED by both batches
//    (w_ih regs freed from steady state by per-chunk xg precompute into LDS).
//  - steady-state DS per step-pair: 24 hbuf b128 broadcast reads + 6 xg b32
//    + 2 b32 writes -- uncontended (1 wave/CU).
//  - h broadcast hybrid: k<16 via v_readlane (starts FMA stream instantly),
//    k>=16 via broadcast ds_read_b128 from double-buffered hbuf (same-wave
//    in-order LDS => no barrier; proven in R5, absmax 0.0).
//  - paired even/odd-k accumulators: shorter chains + SLP-friendly for
//    v_pk_fma_f32 (gfx950 fp32 peak 157TF implies packed dual FMA).
//  - batch A / batch B instruction streams are independent => each fills the
//    other's stalls.

#define Hh 64
#define Dd 16
#define Tt 512
#define Bb 512
#define CH 32    // timesteps per x/xg chunk (LDS budget: xg = 2*3*32*64*4 = 48 KB)
#define NB 2     // batches per wave

__device__ __forceinline__ float sigmoid_fast(float v) {
    return 1.0f / (1.0f + __expf(-v));
}
__device__ __forceinline__ float tanh_fast(float v) {
    float e = __expf(2.0f * v);
    return 1.0f - 2.0f / (e + 1.0f);
}
__device__ __forceinline__ float lane_bcast(float v, int k) {
    return __int_as_float(__builtin_amdgcn_readlane(__float_as_int(v), k));
}
__device__ __forceinline__ float dot4(float4 a, float4 b) {
    return a.x * b.x + a.y * b.y + a.z * b.z + a.w * b.w;
}

__global__ __launch_bounds__(64, 1)
void bigru_fused_kernel(const float* __restrict__ x,
                        const float* __restrict__ w_ih_f, const float* __restrict__ w_hh_f,
                        const float* __restrict__ b_ih_f, const float* __restrict__ b_hh_f,
                        const float* __restrict__ w_ih_b, const float* __restrict__ w_hh_b,
                        const float* __restrict__ b_ih_b, const float* __restrict__ b_hh_b,
                        const float* __restrict__ fc_w,  const float* __restrict__ fc_b,
                        float* __restrict__ out)
{
    const int j  = threadIdx.x;          // hidden unit 0..63 (single wave)
    const int b0 = blockIdx.x * NB;      // first batch of the pair
    const int b1 = b0 + 1;

    __shared__ __align__(16) float xg[NB][3][CH][Hh];   // 48 KB input proj (+bias)
    __shared__ __align__(16) float xbuf[NB][CH * Dd];   // 4 KB raw x chunks
    __shared__ __align__(16) float hbuf[2][NB][Hh];     // 1 KB h broadcast, dbuf

    // ---- ALL recurrent weight rows {j, 64+j, 128+j} in 192 VGPRs (shared) ----
    float wr[Hh], wz[Hh], wn[Hh];
    {
        const float4* r0 = (const float4*)(w_hh_f + (size_t)j            * Hh);
        const float4* r1 = (const float4*)(w_hh_f + (size_t)(Hh + j)     * Hh);
        const float4* r2 = (const float4*)(w_hh_f + (size_t)(2 * Hh + j) * Hh);
#pragma unroll
        for (int q = 0; q < Hh / 4; ++q) {
            float4 a = r0[q]; wr[4*q] = a.x; wr[4*q+1] = a.y; wr[4*q+2] = a.z; wr[4*q+3] = a.w;
            float4 c = r1[q]; wz[4*q] = c.x; wz[4*q+1] = c.y; wz[4*q+2] = c.z; wz[4*q+3] = c.w;
            float4 e = r2[q]; wn[4*q] = e.x; wn[4*q+1] = e.y; wn[4*q+2] = e.z; wn[4*q+3] = e.w;
        }
    }
    const float bxr = b_ih_f[j]          + b_hh_f[j];
    const float bxz = b_ih_f[Hh + j]     + b_hh_f[Hh + j];
    const float bxn = b_ih_f[2 * Hh + j];
    const float bhn = b_hh_f[2 * Hh + j];

    float h0 = 0.0f, h1 = 0.0f;
    hbuf[0][0][j] = 0.0f;
    hbuf[0][1][j] = 0.0f;

    const float* xrow0 = x + (size_t)b0 * Tt * Dd;
    const float* xrow1 = x + (size_t)b1 * Tt * Dd;

    for (int tc = 0; tc < Tt / CH; ++tc) {
        // ---- stage x chunks for both batches (CH*Dd/4 = 128 float4 each) ----
        {
            const float4* s0 = (const float4*)(xrow0 + (size_t)tc * CH * Dd);
            const float4* s1 = (const float4*)(xrow1 + (size_t)tc * CH * Dd);
            float4* d0 = (float4*)xbuf[0];
            float4* d1 = (float4*)xbuf[1];
            d0[j] = s0[j];  d0[64 + j] = s0[64 + j];
            d1[j] = s1[j];  d1[64 + j] = s1[64 + j];
        }

        // ---- precompute input projections (wi transient; freed for recurrence) ----
        {
            float4 wir[4], wiz[4], win[4];
            const float4* p0 = (const float4*)(w_ih_f + (size_t)j            * Dd);
            const float4* p1 = (const float4*)(w_ih_f + (size_t)(Hh + j)     * Dd);
            const float4* p2 = (const float4*)(w_ih_f + (size_t)(2 * Hh + j) * Dd);
#pragma unroll
            for (int q = 0; q < 4; ++q) { wir[q] = p0[q]; wiz[q] = p1[q]; win[q] = p2[q]; }
#pragma unroll
            for (int bb = 0; bb < NB; ++bb) {
                for (int tt = 0; tt < CH; ++tt) {
                    const float4* x4 = (const float4*)(xbuf[bb] + tt * Dd);
                    float4 xv0 = x4[0], xv1 = x4[1], xv2 = x4[2], xv3 = x4[3];
                    xg[bb][0][tt][j] = bxr + dot4(wir[0], xv0) + dot4(wir[1], xv1)
                                           + dot4(wir[2], xv2) + dot4(wir[3], xv3);
                    xg[bb][1][tt][j] = bxz + dot4(wiz[0], xv0) + dot4(wiz[1], xv1)
                                           + dot4(wiz[2], xv2) + dot4(wiz[3], xv3);
                    xg[bb][2][tt][j] = bxn + dot4(win[0], xv0) + dot4(win[1], xv1)
                                           + dot4(win[2], xv2) + dot4(win[3], xv3);
                }
            }
        }

        // ---- recurrence: both batches interleaved, zero barriers ----
        for (int tt = 0; tt < CH; ++tt) {
            const int par = tt & 1;   // CH even => parity lines up across chunks

            // even/odd-k accumulator pairs (chain-split + pk_fma-friendly)
            float arA = xg[0][0][tt][j], azA = xg[0][1][tt][j];
            float xnA = xg[0][2][tt][j], anA = bhn;
            float arA1 = 0.0f, azA1 = 0.0f, anA1 = 0.0f;
            float arB = xg[1][0][tt][j], azB = xg[1][1][tt][j];
            float xnB = xg[1][2][tt][j], anB = bhn;
            float arB1 = 0.0f, azB1 = 0.0f, anB1 = 0.0f;

            const float4* ha4 = (const float4*)(hbuf[par][0]);
            const float4* hb4 = (const float4*)(hbuf[par][1]);

#pragma unroll
            for (int q = 0; q < 16; ++q) {
                float4 hva, hvb;
                if (q < 4) {   // k = 0..15 via readlane: no LDS dependency at step start
                    hva.x = lane_bcast(h0, 4*q+0); hva.y = lane_bcast(h0, 4*q+1);
                    hva.z = lane_bcast(h0, 4*q+2); hva.w = lane_bcast(h0, 4*q+3);
                    hvb.x = lane_bcast(h1, 4*q+0); hvb.y = lane_bcast(h1, 4*q+1);
                    hvb.z = lane_bcast(h1, 4*q+2); hvb.w = lane_bcast(h1, 4*q+3);
                } else {       // k = 16..63 via broadcast b128 (conflict-free)
                    hva = ha4[q];
                    hvb = hb4[q];
                }
                arA  = fmaf(wr[4*q+0], hva.x, arA);  arA1 = fmaf(wr[4*q+1], hva.y, arA1);
                arA  = fmaf(wr[4*q+2], hva.z, arA);  arA1 = fmaf(wr[4*q+3], hva.w, arA1);
                azA  = fmaf(wz[4*q+0], hva.x, azA);  azA1 = fmaf(wz[4*q+1], hva.y, azA1);
                azA  = fmaf(wz[4*q+2], hva.z, azA);  azA1 = fmaf(wz[4*q+3], hva.w, azA1);
                anA  = fmaf(wn[4*q+0], hva.x, anA);  anA1 = fmaf(wn[4*q+1], hva.y, anA1);
                anA  = fmaf(wn[4*q+2], hva.z, anA);  anA1 = fmaf(wn[4*q+3], hva.w, anA1);

                arB  = fmaf(wr[4*q+0], hvb.x, arB);  arB1 = fmaf(wr[4*q+1], hvb.y, arB1);
                arB  = fmaf(wr[4*q+2], hvb.z, arB);  arB1 = fmaf(wr[4*q+3], hvb.w, arB1);
                azB  = fmaf(wz[4*q+0], hvb.x, azB);  azB1 = fmaf(wz[4*q+1], hvb.y, azB1);
                azB  = fmaf(wz[4*q+2], hvb.z, azB);  azB1 = fmaf(wz[4*q+3], hvb.w, azB1);
                anB  = fmaf(wn[4*q+0], hvb.x, anB);  anB1 = fmaf(wn[4*q+1], hvb.y, anB1);
                anB  = fmaf(wn[4*q+2], hvb.z, anB);  anB1 = fmaf(wn[4*q+3], hvb.w, anB1);
            }

            {   // batch A gates
                float ar = arA + arA1, az = azA + azA1, an = anA + anA1;
                float r = sigmoid_fast(ar);
                float z = sigmoid_fast(az);
                float n = tanh_fast(xnA + r * an);
                h0 = n + z * (h0 - n);
            }
            {   // batch B gates
                float ar = arB + arB1, az = azB + azB1, an = anB + anB1;
                float r = sigmoid_fast(ar);
                float z = sigmoid_fast(az);
                float n = tanh_fast(xnB + r * an);
                h1 = n + z * (h1 - n);
            }
            hbuf[par ^ 1][0][j] = h0;   // in-order same-wave LDS: no barrier
            hbuf[par ^ 1][1][j] = h1;
        }
    }

    // ---- backward direction: one cell step from h=0 on x[:,T-1,:], both batches ----
    float hbk[NB];
    {
        float4 q0[4], q1[4], q2[4];
        const float4* p0 = (const float4*)(w_ih_b + (size_t)j            * Dd);
        const float4* p1 = (const float4*)(w_ih_b + (size_t)(Hh + j)     * Dd);
        const float4* p2 = (const float4*)(w_ih_b + (size_t)(2 * Hh + j) * Dd);
#pragma unroll
        for (int q = 0; q < 4; ++q) { q0[q] = p0[q]; q1[q] = p1[q]; q2[q] = p2[q]; }
        const float br2   = b_ih_b[j]          + b_hh_b[j];
        const float bz2   = b_ih_b[Hh + j]     + b_hh_b[Hh + j];
        const float bn2   = b_ih_b[2 * Hh + j];
        const float bhnb  = b_hh_b[2 * Hh + j];
#pragma unroll
        for (int bb = 0; bb < NB; ++bb) {
            const float4* xl = (const float4*)(xbuf[bb] + (CH - 1) * Dd);  // t = 511
            float ar = br2, az = bz2, axn = bn2;
#pragma unroll
            for (int q = 0; q < 4; ++q) {
                float4 xv = xl[q];
                ar  += dot4(q0[q], xv);
                az  += dot4(q1[q], xv);
                axn += dot4(q2[q], xv);
            }
            float rb = sigmoid_fast(ar);
            float zb = sigmoid_fast(az);
            float nb = tanh_fast(axn + rb * bhnb);
            hbk[bb] = (1.0f - zb) * nb;   // h0 = 0
        }
    }

    // ---- fused FC for both batches ----
    float v0 = fc_w[j] * h0 + fc_w[Hh + j] * hbk[0];
    float v1 = fc_w[j] * h1 + fc_w[Hh + j] * hbk[1];
#pragma unroll
    for (int off = 32; off > 0; off >>= 1) {
        v0 += __shfl_xor(v0, off, 64);
        v1 += __shfl_xor(v1, off, 64);
    }
    if (j == 0) {
        out[b0] = v0 + fc_b[0];
        out[b1] = v1 + fc_b[0];
    }
}

extern "C" void kernel_launch(void* const* d_in, const int* in_sizes, int n_in,
                              void* d_out, int out_size, void* d_ws, size_t ws_size,
                              hipStream_t stream) {
    const float* x      = (const float*)d_in[0];
    const float* w_ih_f = (const float*)d_in[1];
    const float* w_hh_f = (const float*)d_in[2];
    const float* b_ih_f = (const float*)d_in[3];
    const float* b_hh_f = (const float*)d_in[4];
    const float* w_ih_b = (const float*)d_in[5];
    const float* w_hh_b = (const float*)d_in[6];
    const float* b_ih_b = (const float*)d_in[7];
    const float* b_hh_b = (const float*)d_in[8];
    const float* fc_w   = (const float*)d_in[9];
    const float* fc_b   = (const float*)d_in[10];

    bigru_fused_kernel<<<dim3(Bb / NB), dim3(64), 0, stream>>>(
        x, w_ih_f, w_hh_f, b_ih_f, b_hh_f,
        w_ih_b, w_hh_b, b_ih_b, b_hh_b, fc_w, fc_b,
        (float*)d_out);
}

// Round 7
// 431.756 us; speedup vs baseline: 1.7240x; 1.7240x over previous
//
#include <hip/hip_runtime.h>

// BiGRU, B=512, T=512, D=16, H=64.
// Backward direction needs only ONE cell step (ys_b[0] = GRUCell(x[:,T-1,:], 0)).
//
// Ladder so far: R4 4-wave K-split + barrier = 379us (champion); R5 1-wave
// barrier-free = 483; R6 2-batch/wave = 694 (1 wave/CU too few). R4's costs:
// ~144 DS ops/step/CU contending + 2 waves/SIMD doubling issue time.
//
// This version: 2-wave K-split (KW=32), 512 blocks x 128 thr:
//  - 1024 waves on 1024 SIMDs: every SIMD holds exactly 1 wave.
//  - wave w holds cols [32w,32w+32) of w_hh rows {j,64+j,128+j}: 96 VGPRs.
//  - full h REPLICATED in registers in both waves (no hbuf LDS at all);
//    own k-slice via v_readlane.
//  - per step: 96 FMA + 3 partial ds_writes + ONE barrier (parity slots) +
//    6 partial reads. BOTH waves read BOTH partials and add in the same
//    order -> bitwise-identical h (no -ffast-math reassociation assumed).
//  - xg (input proj + bias) precomputed per 64-step chunk, tt split by wave.

#define Hh 64
#define Dd 16
#define Tt 512
#define Bb 512
#define CH 64   // timesteps per chunk
#define NW 2    // waves per block
#define KW 32   // k-columns per wave

__device__ __forceinline__ float sigmoid_fast(float v) {
    return 1.0f / (1.0f + __expf(-v));
}
__device__ __forceinline__ float tanh_fast(float v) {
    float e = __expf(2.0f * v);
    return 1.0f - 2.0f / (e + 1.0f);
}
__device__ __forceinline__ float lane_bcast(float v, int k) {
    return __int_as_float(__builtin_amdgcn_readlane(__float_as_int(v), k));
}
__device__ __forceinline__ float dot4(float4 a, float4 b) {
    return a.x * b.x + a.y * b.y + a.z * b.z + a.w * b.w;
}

__global__ __launch_bounds__(128, 1)
void bigru_fused_kernel(const float* __restrict__ x,
                        const float* __restrict__ w_ih_f, const float* __restrict__ w_hh_f,
                        const float* __restrict__ b_ih_f, const float* __restrict__ b_hh_f,
                        const float* __restrict__ w_ih_b, const float* __restrict__ w_hh_b,
                        const float* __restrict__ b_ih_b, const float* __restrict__ b_hh_b,
                        const float* __restrict__ fc_w,  const float* __restrict__ fc_b,
                        float* __restrict__ out)
{
    const int tid = threadIdx.x;
    const int j   = tid & 63;           // hidden unit
    const int w   = tid >> 6;           // wave id 0..1
    const int b   = blockIdx.x;         // batch element
    const int k0  = __builtin_amdgcn_readfirstlane(w << 5);   // 0 or 32

    __shared__ __align__(16) float xg[3][CH][Hh];        // 48 KB input proj (+bias)
    __shared__ __align__(16) float xbuf[CH * Dd];        // 4 KB raw x chunk
    __shared__ __align__(16) float parts[2][NW][3][Hh];  // 6 KB partials (parity dbuf)

    // ---- recurrent weights: rows {j,64+j,128+j}, cols [k0,k0+32) -> 96 VGPRs ----
    float wr[KW], wz[KW], wn[KW];
    {
        const float4* r0 = (const float4*)(w_hh_f + (size_t)j            * Hh + k0);
        const float4* r1 = (const float4*)(w_hh_f + (size_t)(Hh + j)     * Hh + k0);
        const float4* r2 = (const float4*)(w_hh_f + (size_t)(2 * Hh + j) * Hh + k0);
#pragma unroll
        for (int q = 0; q < KW / 4; ++q) {
            float4 a = r0[q]; wr[4*q] = a.x; wr[4*q+1] = a.y; wr[4*q+2] = a.z; wr[4*q+3] = a.w;
            float4 c = r1[q]; wz[4*q] = c.x; wz[4*q+1] = c.y; wz[4*q+2] = c.z; wz[4*q+3] = c.w;
            float4 e = r2[q]; wn[4*q] = e.x; wn[4*q+1] = e.y; wn[4*q+2] = e.z; wn[4*q+3] = e.w;
        }
    }
    // ---- input-projection weights (hoisted, 48 regs) + biases ----
    float4 wir[4], wiz[4], win[4];
    {
        const float4* p0 = (const float4*)(w_ih_f + (size_t)j            * Dd);
        const float4* p1 = (const float4*)(w_ih_f + (size_t)(Hh + j)     * Dd);
        const float4* p2 = (const float4*)(w_ih_f + (size_t)(2 * Hh + j) * Dd);
#pragma unroll
        for (int q = 0; q < 4; ++q) { wir[q] = p0[q]; wiz[q] = p1[q]; win[q] = p2[q]; }
    }
    const float bxr = b_ih_f[j]          + b_hh_f[j];
    const float bxz = b_ih_f[Hh + j]     + b_hh_f[Hh + j];
    const float bxn = b_ih_f[2 * Hh + j];
    const float bhn = b_hh_f[2 * Hh + j];

    float h = 0.0f;   // full h replicated per wave (identical arithmetic)
    const float* xrow = x + (size_t)b * Tt * Dd;

    for (int tc = 0; tc < Tt / CH; ++tc) {
        __syncthreads();  // previous chunk's xg/xbuf fully consumed
        // stage 64 timesteps (1024 floats = 256 float4): 2 per thread, coalesced
        {
            const float4* src = (const float4*)(xrow + (size_t)tc * CH * Dd);
            float4* dst = (float4*)xbuf;
            dst[tid] = src[tid];
            dst[128 + tid] = src[128 + tid];
        }
        __syncthreads();

        // ---- precompute input projections: wave w covers tt in [32w,32w+32) ----
        for (int tt2 = 0; tt2 < KW; ++tt2) {
            const int tt = k0 + tt2;
            const float4* x4 = (const float4*)(xbuf + tt * Dd);
            float4 xv0 = x4[0], xv1 = x4[1], xv2 = x4[2], xv3 = x4[3];
            xg[0][tt][j] = bxr + dot4(wir[0], xv0) + dot4(wir[1], xv1)
                               + dot4(wir[2], xv2) + dot4(wir[3], xv3);
            xg[1][tt][j] = bxz + dot4(wiz[0], xv0) + dot4(wiz[1], xv1)
                               + dot4(wiz[2], xv2) + dot4(wiz[3], xv3);
            xg[2][tt][j] = bxn + dot4(win[0], xv0) + dot4(win[1], xv1)
                               + dot4(win[2], xv2) + dot4(win[3], xv3);
        }
        __syncthreads();

        // ---- recurrence: K-split matvec, ONE barrier per step ----
        for (int tt = 0; tt < CH; ++tt) {
            const int par = tt & 1;   // CH even => parity consistent across chunks

            // prefetch step-local xg early (independent of parts)
            float xgr = xg[0][tt][j];
            float xgz = xg[1][tt][j];
            float xgn = xg[2][tt][j];

            float pr = 0.0f, pz = 0.0f, pn = 0.0f;
#pragma unroll
            for (int kk = 0; kk < KW; ++kk) {
                float hk = lane_bcast(h, k0 + kk);
                pr = fmaf(wr[kk], hk, pr);
                pz = fmaf(wz[kk], hk, pz);
                pn = fmaf(wn[kk], hk, pn);
            }
            parts[par][w][0][j] = pr;
            parts[par][w][1][j] = pz;
            parts[par][w][2][j] = pn;
            __syncthreads();

            // both waves read BOTH partials, same order -> identical h bitwise
            float ar = xgr + parts[par][0][0][j] + parts[par][1][0][j];
            float az = xgz + parts[par][0][1][j] + parts[par][1][1][j];
            float an = bhn + parts[par][0][2][j] + parts[par][1][2][j];

            float r = sigmoid_fast(ar);
            float z = sigmoid_fast(az);
            float n = tanh_fast(xgn + r * an);
            h = n + z * (h - n);   // (1-z)*n + z*h
        }
    }

    // ---- tail: backward single cell step + FC, wave 0 only ----
    if (w == 0) {
        float ar   = b_ih_b[j]          + b_hh_b[j];
        float az   = b_ih_b[Hh + j]     + b_hh_b[Hh + j];
        float axn  = b_ih_b[2 * Hh + j];
        float bhnb = b_hh_b[2 * Hh + j];
        {
            const float4* xl = (const float4*)(xbuf + (CH - 1) * Dd);  // t = 511
            const float4* q0 = (const float4*)(w_ih_b + (size_t)j            * Dd);
            const float4* q1 = (const float4*)(w_ih_b + (size_t)(Hh + j)     * Dd);
            const float4* q2 = (const float4*)(w_ih_b + (size_t)(2 * Hh + j) * Dd);
#pragma unroll
            for (int q = 0; q < 4; ++q) {
                float4 xv = xl[q];
                ar  += dot4(q0[q], xv);
                az  += dot4(q1[q], xv);
                axn += dot4(q2[q], xv);
            }
        }
        float rb = sigmoid_fast(ar);
        float zb = sigmoid_fast(az);
        float nb = tanh_fast(axn + rb * bhnb);
        float hb = (1.0f - zb) * nb;   // h0 = 0

        float v = fc_w[j] * h + fc_w[Hh + j] * hb;
#pragma unroll
        for (int off = 32; off > 0; off >>= 1)
            v += __shfl_xor(v, off, 64);
        if (j == 0) out[b] = v + fc_b[0];
    }
}

extern "C" void kernel_launch(void* const* d_in, const int* in_sizes, int n_in,
                              void* d_out, int out_size, void* d_ws, size_t ws_size,
                              hipStream_t stream) {
    const float* x      = (const float*)d_in[0];
    const float* w_ih_f = (const float*)d_in[1];
    const float* w_hh_f = (const float*)d_in[2];
    const float* b_ih_f = (const float*)d_in[3];
    const float* b_hh_f = (const float*)d_in[4];
    const float* w_ih_b = (const float*)d_in[5];
    const float* w_hh_b = (const float*)d_in[6];
    const float* b_ih_b = (const float*)d_in[7];
    const float* b_hh_b = (const float*)d_in[8];
    const float* fc_w   = (const float*)d_in[9];
    const float* fc_b   = (const float*)d_in[10];

    bigru_fused_kernel<<<dim3(Bb), dim3(NW * 64), 0, stream>>>(
        x, w_ih_f, w_hh_f, b_ih_f, b_hh_f,
        w_ih_b, w_hh_b, b_ih_b, b_hh_b, fc_w, fc_b,
        (float*)d_out);
}